// Round 2
// 1993.007 us; speedup vs baseline: 1.1664x; 1.1664x over previous
//
#include <hip/hip_runtime.h>
#include <cstdint>
#include <cstddef>

namespace {

constexpr int T_DIM = 8192;   // tokens
constexpr int D_DIM = 4096;   // d_in (K)
constexpr int U_DIM = 16384;  // units (N)

typedef float f32x4 __attribute__((ext_vector_type(4)));

__device__ __forceinline__ void gl_lds16(const void* g, void* l) {
  typedef const __attribute__((address_space(1))) unsigned int* gp_t;
  typedef __attribute__((address_space(3))) unsigned int* lp_t;
  __builtin_amdgcn_global_load_lds((gp_t)g, (lp_t)l, 16, 0, 0);
}

// ---------------- amax reduction (float bits atomicMax; all values >= 0) ----
__global__ void amax_kernel(const float4* __restrict__ p, int n4,
                            unsigned* __restrict__ out) {
  float m = 0.f;
  const int stride = gridDim.x * blockDim.x;
  for (int i = blockIdx.x * blockDim.x + threadIdx.x; i < n4; i += stride) {
    float4 v = p[i];
    m = fmaxf(m, fmaxf(fmaxf(fabsf(v.x), fabsf(v.y)),
                       fmaxf(fabsf(v.z), fabsf(v.w))));
  }
#pragma unroll
  for (int off = 32; off > 0; off >>= 1)
    m = fmaxf(m, __shfl_down(m, off, 64));
  if ((threadIdx.x & 63) == 0) atomicMax(out, __float_as_uint(m));
}

// ---------------- quantize x: f32 [T][D] -> fp8 [T][D] ---------------------
__global__ void quant_x_kernel(const float4* __restrict__ x,
                               unsigned* __restrict__ xq, int n4,
                               const unsigned* __restrict__ amax_bits) {
  const float s = 448.f / fmaxf(__uint_as_float(amax_bits[0]), 1e-12f);
  const int stride = gridDim.x * blockDim.x;
  for (int i = blockIdx.x * blockDim.x + threadIdx.x; i < n4; i += stride) {
    float4 v = x[i];
    int pk = 0;
    pk = __builtin_amdgcn_cvt_pk_fp8_f32(v.x * s, v.y * s, pk, false);
    pk = __builtin_amdgcn_cvt_pk_fp8_f32(v.z * s, v.w * s, pk, true);
    xq[i] = (unsigned)pk;
  }
}

// ------- quantize + transpose kernel: f32 [D][U] -> fp8 [U][D] -------------
__global__ void quant_kT_kernel(const float* __restrict__ k,
                                unsigned char* __restrict__ kq,
                                const unsigned* __restrict__ amax_bits) {
  __shared__ float smf[64 * 65];  // [u_local][d_local], pad to break banks
  const float s = 448.f / fmaxf(__uint_as_float(amax_bits[1]), 1e-12f);
  const int u0 = blockIdx.x * 64, d0 = blockIdx.y * 64;
  const int t = threadIdx.x;
  const int r0 = t >> 4, c4 = (t & 15) << 2;
#pragma unroll
  for (int rr = r0; rr < 64; rr += 16) {
    float4 v = *(const float4*)(k + (size_t)(d0 + rr) * U_DIM + u0 + c4);
    smf[(c4 + 0) * 65 + rr] = v.x;
    smf[(c4 + 1) * 65 + rr] = v.y;
    smf[(c4 + 2) * 65 + rr] = v.z;
    smf[(c4 + 3) * 65 + rr] = v.w;
  }
  __syncthreads();
#pragma unroll
  for (int rr = r0; rr < 64; rr += 16) {
    float a = smf[rr * 65 + c4 + 0];
    float b = smf[rr * 65 + c4 + 1];
    float c = smf[rr * 65 + c4 + 2];
    float d = smf[rr * 65 + c4 + 3];
    int pk = 0;
    pk = __builtin_amdgcn_cvt_pk_fp8_f32(a * s, b * s, pk, false);
    pk = __builtin_amdgcn_cvt_pk_fp8_f32(c * s, d * s, pk, true);
    *(unsigned*)(kq + (size_t)(u0 + rr) * D_DIM + d0 + c4) = (unsigned)pk;
  }
}

// ---------------- fp8 GEMM + dequant + bias + gelu -------------------------
// A: fp8 [T][D] row-major.  B: fp8 [U][D] row-major (pre-transposed kernel).
// 256x256 block tile, BK=128 (128B rows), 8 waves (2Mx4N), 512 threads.
// 4-phase-per-K-tile schedule: counted vmcnt (never 0 except final tile),
// raw s_barrier, setprio around MFMA clusters, XOR-8 chunk swizzle on LDS
// (pre-swizzled global source so global_load_lds dest stays linear).
//
// LDS map (131072 B): A buf0 @0, A buf1 @32768, B buf0 @65536, B buf1 @98304.
// Each buf = 256 rows x 128 B. Quarter q = rows q..q+63 (full 128B of K),
// one global_load_lds round of 512 x 16 B.
//
// Stage order during tile t (for tile t+1, into the other buffer):
//   ph0: B(0), B(128)   ph1: B(64), B(192)
//   ph2: A(0), A(128)   ph3: A(64), A(192)
// vmcnt ledger (per thread, ops complete oldest-first):
//   ph3 vmcnt(2): 8 outstanding -> drains all B + A(0),A(128) of t+1;
//                 leaves A(64),A(192) in flight.   (read at t+1 ph0)
//   ph1 vmcnt(4): 6 outstanding -> drains A(64),A(192) of current tile.
//                 (read at ph2)
//   FINAL body stages nothing -> ph1 must use vmcnt(0) (vmcnt(4) would be
//   a no-op with only 2 outstanding -> race; this was round-1's tripwire).

#define BAR() __builtin_amdgcn_s_barrier()
#define WLGKM() asm volatile("s_waitcnt lgkmcnt(0)" ::: "memory")
#define WVM_(N) asm volatile("s_waitcnt vmcnt(" #N ")" ::: "memory")
#define WVM(N) WVM_(N)
#define SBAR0() __builtin_amdgcn_sched_barrier(0)

#define LDA(MH)                                                         \
  do {                                                                  \
    _Pragma("unroll") for (int q2 = 0; q2 < 4; ++q2) {                  \
      _Pragma("unroll") for (int ks = 0; ks < 4; ++ks) {                \
        aR[q2][ks] = *(const long long*)&sh[aks[ks] +                   \
                                            ((MH)*64 + q2 * 16) * 128]; \
      }                                                                 \
    }                                                                   \
  } while (0)

#define LDB(NH)                                                       \
  do {                                                                \
    _Pragma("unroll") for (int j = 0; j < 2; ++j) {                   \
      _Pragma("unroll") for (int ks = 0; ks < 4; ++ks) {              \
        bR[j][ks] =                                                   \
            *(const long long*)&sh[bks[ks] + ((NH)*2 + j) * 2048];    \
      }                                                               \
    }                                                                 \
  } while (0)

#define MQ(MH, NH)                                                        \
  do {                                                                    \
    _Pragma("unroll") for (int ks = 0; ks < 4; ++ks) {                    \
      _Pragma("unroll") for (int q2 = 0; q2 < 4; ++q2) {                  \
        _Pragma("unroll") for (int j = 0; j < 2; ++j) {                   \
          acc[(MH)*4 + q2][(NH)*2 + j] =                                  \
              __builtin_amdgcn_mfma_f32_16x16x32_fp8_fp8(                 \
                  aR[q2][ks], bR[j][ks], acc[(MH)*4 + q2][(NH)*2 + j], 0, \
                  0, 0);                                                  \
        }                                                                 \
      }                                                                   \
    }                                                                     \
  } while (0)

// stage one 64-row quarter: 1 global_load_lds round (512 lanes x 16 B)
#define STG_A(ROFF, LOFF, KB1) \
  gl_lds16(gA + (size_t)(ROFF)*D_DIM + (KB1), &sh[(LOFF) + ldst])
#define STG_B(ROFF, LOFF, KB1) \
  gl_lds16(gB + (size_t)(ROFF)*D_DIM + (KB1), &sh[65536 + (LOFF) + ldst])

#define TILE_BODY(ABUF, ANEXT, KB1, ST, VM1)                              \
  do {                                                                    \
    int aks[4], bks[4];                                                   \
    _Pragma("unroll") for (int ks = 0; ks < 4; ++ks) {                    \
      aks[ks] = ((ABUF) + arow) ^ (ks << 5);                              \
      bks[ks] = ((ABUF) + brow) ^ (ks << 5);                              \
    }                                                                     \
    /* ---- phase 0: quadrant (mh0, nh0) ---- */                          \
    LDA(0);                                                               \
    LDB(0);                                                               \
    if (ST) {                                                             \
      STG_B(0, (ANEXT) + 0, KB1);                                         \
      STG_B(128, (ANEXT) + 16384, KB1);                                   \
    }                                                                     \
    BAR();                                                                \
    WLGKM();                                                              \
    __builtin_amdgcn_s_setprio(1);                                        \
    MQ(0, 0);                                                             \
    __builtin_amdgcn_s_setprio(0);                                        \
    BAR();                                                                \
    /* ---- phase 1: (mh0, nh1) ---- */                                   \
    LDB(1);                                                               \
    if (ST) {                                                             \
      STG_B(64, (ANEXT) + 8192, KB1);                                     \
      STG_B(192, (ANEXT) + 24576, KB1);                                   \
    }                                                                     \
    BAR();                                                                \
    WLGKM();                                                              \
    __builtin_amdgcn_s_setprio(1);                                        \
    MQ(0, 1);                                                             \
    __builtin_amdgcn_s_setprio(0);                                        \
    WVM(VM1);                                                             \
    BAR();                                                                \
    SBAR0(); /* keep ph2's ds_reads below the cross-wave barrier */       \
    /* ---- phase 2: (mh1, nh0) ---- */                                   \
    LDA(1);                                                               \
    LDB(0);                                                               \
    if (ST) {                                                             \
      STG_A(0, (ANEXT) + 0, KB1);                                         \
      STG_A(128, (ANEXT) + 16384, KB1);                                   \
    }                                                                     \
    BAR();                                                                \
    WLGKM();                                                              \
    __builtin_amdgcn_s_setprio(1);                                        \
    MQ(1, 0);                                                             \
    __builtin_amdgcn_s_setprio(0);                                        \
    BAR();                                                                \
    /* ---- phase 3: (mh1, nh1) ---- */                                   \
    LDB(1);                                                               \
    if (ST) {                                                             \
      STG_A(64, (ANEXT) + 8192, KB1);                                     \
      STG_A(192, (ANEXT) + 24576, KB1);                                   \
    }                                                                     \
    BAR();                                                                \
    WLGKM();                                                              \
    __builtin_amdgcn_s_setprio(1);                                        \
    MQ(1, 1);                                                             \
    __builtin_amdgcn_s_setprio(0);                                        \
    WVM(2);                                                               \
    BAR();                                                                \
    SBAR0(); /* keep next body's ph0 ds_reads below the barrier */        \
  } while (0)

__global__ __launch_bounds__(512, 2) void gemm_fp8_kernel(
    const unsigned char* __restrict__ A, const unsigned char* __restrict__ B,
    const float* __restrict__ bias, const unsigned* __restrict__ amax_bits,
    float* __restrict__ out) {
  __shared__ __align__(128) unsigned char sh[131072];

  const int tid = threadIdx.x;
  const int lane = tid & 63;
  const int wave = tid >> 6;
  const int wr = wave >> 2, wc = wave & 3;  // 2 x 4 wave grid
  const int lane15 = lane & 15;

  // XCD-bijective block swizzle (nwg = 2048, 2048 % 8 == 0)
  const int bid = (int)blockIdx.y * 64 + (int)blockIdx.x;
  const int swz = (bid & 7) * 256 + (bid >> 3);
  const size_t m0 = (size_t)(swz >> 6) * 256;  // 32 M-blocks
  const size_t n0 = (size_t)(swz & 63) * 256;  // 64 N-blocks

  const float sx = 448.f / fmaxf(__uint_as_float(amax_bits[0]), 1e-12f);
  const float sk = 448.f / fmaxf(__uint_as_float(amax_bits[1]), 1e-12f);
  const float inv_s = 1.f / (sx * sk);

  // Staging: thread t moves 16B; LDS dest linear (quarter base + t*16),
  // global source chunk pre-swizzled: chunk = (t&7) ^ (row&7).
  const int srow = tid >> 3;                          // 0..63 within quarter
  const int schunk = (((tid & 7) ^ (srow & 7)) << 4); // byte offset 0..112
  const unsigned char* gA = A + (m0 + srow) * D_DIM + schunk;
  const unsigned char* gB = B + (n0 + srow) * D_DIM + schunk;
  const int ldst = tid * 16;

  // Fragment reads: row = <frag base> + lane15; k-byte kb = ks*32 + g*8,
  // g = lane>>4.  Swizzled LDS offset low bits = kb ^ ((row&7)<<4); since
  // row&7 == lane&7, precompute kgs and XOR ks<<5 per read (bits 5-6 only;
  // frag-base offsets are multiples of 2048 so adds don't carry into them).
  const int kgs = (((lane >> 4) << 3) ^ ((lane & 7) << 4));
  const int arow = (wr * 128 + lane15) * 128 + kgs;          // + buf*32768
  const int brow = 65536 + (wc * 64 + lane15) * 128 + kgs;   // + buf*32768

  f32x4 acc[8][4];
#pragma unroll
  for (int i = 0; i < 8; ++i)
#pragma unroll
    for (int j = 0; j < 4; ++j) acc[i][j] = (f32x4){0.f, 0.f, 0.f, 0.f};
  long long aR[4][4];
  long long bR[2][4];

  // Prologue: stage K-tile 0 into buf 0 (8 quarters), full drain once.
  STG_B(0, 0, 0);
  STG_B(128, 16384, 0);
  STG_B(64, 8192, 0);
  STG_B(192, 24576, 0);
  STG_A(0, 0, 0);
  STG_A(128, 16384, 0);
  STG_A(64, 8192, 0);
  STG_A(192, 24576, 0);
  asm volatile("s_waitcnt vmcnt(0)" ::: "memory");
  BAR();
  SBAR0();

  // Main loop: 32 K-tiles; 2 bodies/iter so buffer offsets are compile-time.
  // Last pair peeled: final body stages nothing -> ph1 needs vmcnt(0).
  for (int tp = 0; tp < 15; ++tp) {
    const size_t kb1a = (size_t)(2 * tp + 1) * 128;
    const size_t kb1b = (size_t)(2 * tp + 2) * 128;
    TILE_BODY(0, 32768, kb1a, true, 4);
    TILE_BODY(32768, 0, kb1b, true, 4);
  }
  TILE_BODY(0, 32768, (size_t)31 * 128, true, 4);
  TILE_BODY(32768, 0, (size_t)0, false, 0);

  // Epilogue: C/D layout col=lane&15, row=(lane>>4)*4+r.
  const int q4 = (lane >> 4) << 2;
  float bj[4];
#pragma unroll
  for (int j = 0; j < 4; ++j)
    bj[j] = bias[n0 + wc * 64 + j * 16 + lane15];

#pragma unroll
  for (int i = 0; i < 8; ++i) {
    const size_t grow_base = m0 + (size_t)(wr * 128 + i * 16 + q4);
#pragma unroll
    for (int r = 0; r < 4; ++r) {
      float* orow = out + (grow_base + r) * U_DIM + n0 + wc * 64 + lane15;
#pragma unroll
      for (int j = 0; j < 4; ++j) {
        float v = acc[i][j][r] * inv_s + bj[j];
        // tanh-approx gelu, overflow-safe tanh form
        float uu = 0.7978845608028654f * (v + 0.044715f * v * v * v);
        float e = __expf(2.f * uu);
        float th = 1.f - 2.f / (e + 1.f);
        orow[j * 16] = 0.5f * v * (1.f + th);
      }
    }
  }
}

}  // namespace

extern "C" void kernel_launch(void* const* d_in, const int* in_sizes, int n_in,
                              void* d_out, int out_size, void* d_ws,
                              size_t ws_size, hipStream_t stream) {
  const float* x = (const float*)d_in[0];
  const float* kern = (const float*)d_in[1];
  const float* bias = (const float*)d_in[2];
  float* out = (float*)d_out;

  unsigned char* ws = (unsigned char*)d_ws;
  unsigned* amax_bits = (unsigned*)ws;  // [0]=amax(x) bits, [1]=amax(kernel)
  unsigned char* xq = ws + 256;                                  // 32 MB
  unsigned char* kqt = ws + 256 + (size_t)T_DIM * D_DIM;         // 64 MB

  // ws is poisoned 0xAA before every call — zero the amax accumulators.
  hipMemsetAsync(d_ws, 0, 8, stream);

  amax_kernel<<<2048, 256, 0, stream>>>((const float4*)x, T_DIM * D_DIM / 4,
                                        amax_bits + 0);
  amax_kernel<<<4096, 256, 0, stream>>>((const float4*)kern, D_DIM * U_DIM / 4,
                                        amax_bits + 1);
  quant_x_kernel<<<2048, 256, 0, stream>>>((const float4*)x, (unsigned*)xq,
                                           T_DIM * D_DIM / 4, amax_bits);
  quant_kT_kernel<<<dim3(U_DIM / 64, D_DIM / 64), 256, 0, stream>>>(
      kern, kqt, amax_bits);
  gemm_fp8_kernel<<<dim3(U_DIM / 256, T_DIM / 256), 512, 0, stream>>>(
      xq, kqt, bias, amax_bits, out);
}

// Round 3
// 1834.668 us; speedup vs baseline: 1.2671x; 1.0863x over previous
//
#include <hip/hip_runtime.h>
#include <cstdint>
#include <cstddef>

namespace {

constexpr int T_DIM = 8192;   // tokens
constexpr int D_DIM = 4096;   // d_in (K)
constexpr int U_DIM = 16384;  // units (N)

typedef float f32x4 __attribute__((ext_vector_type(4)));

__device__ __forceinline__ void gl_lds16(const void* g, void* l) {
  typedef const __attribute__((address_space(1))) unsigned int* gp_t;
  typedef __attribute__((address_space(3))) unsigned int* lp_t;
  __builtin_amdgcn_global_load_lds((gp_t)g, (lp_t)l, 16, 0, 0);
}

// ---------------- amax reduction (float bits atomicMax; all values >= 0) ----
__global__ void amax_kernel(const float4* __restrict__ p, int n4,
                            unsigned* __restrict__ out) {
  float m = 0.f;
  const int stride = gridDim.x * blockDim.x;
  for (int i = blockIdx.x * blockDim.x + threadIdx.x; i < n4; i += stride) {
    float4 v = p[i];
    m = fmaxf(m, fmaxf(fmaxf(fabsf(v.x), fabsf(v.y)),
                       fmaxf(fabsf(v.z), fabsf(v.w))));
  }
#pragma unroll
  for (int off = 32; off > 0; off >>= 1)
    m = fmaxf(m, __shfl_down(m, off, 64));
  if ((threadIdx.x & 63) == 0) atomicMax(out, __float_as_uint(m));
}

// ---------------- quantize x: f32 [T][D] -> fp8 [T][D] ---------------------
__global__ void quant_x_kernel(const float4* __restrict__ x,
                               unsigned* __restrict__ xq, int n4,
                               const unsigned* __restrict__ amax_bits) {
  const float s = 448.f / fmaxf(__uint_as_float(amax_bits[0]), 1e-12f);
  const int stride = gridDim.x * blockDim.x;
  for (int i = blockIdx.x * blockDim.x + threadIdx.x; i < n4; i += stride) {
    float4 v = x[i];
    int pk = 0;
    pk = __builtin_amdgcn_cvt_pk_fp8_f32(v.x * s, v.y * s, pk, false);
    pk = __builtin_amdgcn_cvt_pk_fp8_f32(v.z * s, v.w * s, pk, true);
    xq[i] = (unsigned)pk;
  }
}

// ------- quantize + transpose kernel: f32 [D][U] -> fp8 [U][D] -------------
__global__ void quant_kT_kernel(const float* __restrict__ k,
                                unsigned char* __restrict__ kq,
                                const unsigned* __restrict__ amax_bits) {
  __shared__ float smf[64 * 65];  // [u_local][d_local], pad to break banks
  const float s = 448.f / fmaxf(__uint_as_float(amax_bits[1]), 1e-12f);
  const int u0 = blockIdx.x * 64, d0 = blockIdx.y * 64;
  const int t = threadIdx.x;
  const int r0 = t >> 4, c4 = (t & 15) << 2;
#pragma unroll
  for (int rr = r0; rr < 64; rr += 16) {
    float4 v = *(const float4*)(k + (size_t)(d0 + rr) * U_DIM + u0 + c4);
    smf[(c4 + 0) * 65 + rr] = v.x;
    smf[(c4 + 1) * 65 + rr] = v.y;
    smf[(c4 + 2) * 65 + rr] = v.z;
    smf[(c4 + 3) * 65 + rr] = v.w;
  }
  __syncthreads();
#pragma unroll
  for (int rr = r0; rr < 64; rr += 16) {
    float a = smf[rr * 65 + c4 + 0];
    float b = smf[rr * 65 + c4 + 1];
    float c = smf[rr * 65 + c4 + 2];
    float d = smf[rr * 65 + c4 + 3];
    int pk = 0;
    pk = __builtin_amdgcn_cvt_pk_fp8_f32(a * s, b * s, pk, false);
    pk = __builtin_amdgcn_cvt_pk_fp8_f32(c * s, d * s, pk, true);
    *(unsigned*)(kq + (size_t)(u0 + rr) * D_DIM + d0 + c4) = (unsigned)pk;
  }
}

// ---------------- fp8 GEMM + dequant + bias + gelu -------------------------
// A: fp8 [T][D] row-major.  B: fp8 [U][D] row-major (pre-transposed kernel).
// 256x256 block tile, BK=128 (128B rows), 8 waves (2Mx4N), 512 threads.
// 2-phase-per-K-tile schedule: B fragments held whole-tile in registers
// (bR[4][4], read ONCE per tile -- round-2 read them twice); A streamed
// per-q2 inside the MFMA cluster.  Counted vmcnt (never 0 except final
// tile), raw s_barrier (3/tile), setprio around MFMA, XOR-8 chunk swizzle
// (pre-swizzled global source, linear global_load_lds dest).
//
// LDS map (131072 B): A buf0 @0, A buf1 @32768, B buf0 @65536, B buf1 @98304.
// Each buf = 256 rows x 128 B. Quarter q = rows q..q+63 (full 128B of K),
// one global_load_lds round of 512 x 16 B.
//
// Stage order during tile t (for tile t+1, into the other buffer):
//   ph0: B(0), B(128), B(64), B(192)      ph1: A(0), A(128), A(64), A(192)
// vmcnt ledger (per thread, FIFO):
//   ph1 end WVM(2): 8 outstanding -> drains B(t+1)x4 + A0,A128(t+1);
//                   leaves A64,A192(t+1) in flight. (read at t+1 ph1)
//   ph0 end WVM(4): 6 outstanding -> drains A64,A192(t). (read at ph1)
//   FINAL tile stages nothing -> ph0 end must drain to 0 (round-1 lesson:
//   a counted vmcnt with too few outstanding ops is a silent no-op race).

#define BAR() __builtin_amdgcn_s_barrier()
#define WLGKM() asm volatile("s_waitcnt lgkmcnt(0)" ::: "memory")
#define WVM_(N) asm volatile("s_waitcnt vmcnt(" #N ")" ::: "memory")
#define WVM(N) WVM_(N)
#define SBAR0() __builtin_amdgcn_sched_barrier(0)

// all 16 B fragments for the tile (wave's 64 B-rows x BK=128)
#define LDB_ALL()                                                   \
  do {                                                              \
    _Pragma("unroll") for (int jb = 0; jb < 4; ++jb) {              \
      _Pragma("unroll") for (int ks = 0; ks < 4; ++ks) {            \
        bR[jb][ks] = *(const long long*)&sh[bks[ks] + jb * 2048];   \
      }                                                             \
    }                                                               \
  } while (0)

// one q2 row-block of A fragments (4 ks slices)
#define LDA4(MH, Q2)                                                \
  do {                                                              \
    _Pragma("unroll") for (int ks = 0; ks < 4; ++ks) {              \
      aR[ks] = *(const long long*)&sh[aks[ks] +                     \
                                      ((MH)*64 + (Q2)*16) * 128];   \
    }                                                               \
  } while (0)

// 16 MFMAs for one (mh, q2) against all held B fragments
#define MQ16(MH, Q2)                                                      \
  do {                                                                    \
    _Pragma("unroll") for (int ks = 0; ks < 4; ++ks) {                    \
      _Pragma("unroll") for (int jb = 0; jb < 4; ++jb) {                  \
        acc[(MH)*4 + (Q2)][jb] =                                          \
            __builtin_amdgcn_mfma_f32_16x16x32_fp8_fp8(                   \
                aR[ks], bR[jb][ks], acc[(MH)*4 + (Q2)][jb], 0, 0, 0);     \
      }                                                                   \
    }                                                                     \
  } while (0)

// stage one 64-row quarter: 1 global_load_lds round (512 lanes x 16 B)
#define STG_A(ROFF, LOFF, KB1) \
  gl_lds16(gA + (size_t)(ROFF)*D_DIM + (KB1), &sh[(LOFF) + ldst])
#define STG_B(ROFF, LOFF, KB1) \
  gl_lds16(gB + (size_t)(ROFF)*D_DIM + (KB1), &sh[65536 + (LOFF) + ldst])

#define TILE2(ABUF, ANEXT, KB1, ST, VMP0, VMP1)                           \
  do {                                                                    \
    int aks[4], bks[4];                                                   \
    _Pragma("unroll") for (int ks = 0; ks < 4; ++ks) {                    \
      aks[ks] = ((ABUF) + arow) ^ (ks << 5);                              \
      bks[ks] = ((ABUF) + brow) ^ (ks << 5);                              \
    }                                                                     \
    /* ---- phase 0: mh0 ---- */                                          \
    LDB_ALL();                                                            \
    if (ST) {                                                             \
      STG_B(0, (ANEXT) + 0, KB1);                                         \
      STG_B(128, (ANEXT) + 16384, KB1);                                   \
      STG_B(64, (ANEXT) + 8192, KB1);                                     \
      STG_B(192, (ANEXT) + 24576, KB1);                                   \
    }                                                                     \
    BAR();                                                                \
    WLGKM(); /* bR retired */                                             \
    __builtin_amdgcn_s_setprio(1);                                        \
    _Pragma("unroll") for (int q2 = 0; q2 < 4; ++q2) {                    \
      LDA4(0, q2);                                                        \
      MQ16(0, q2);                                                        \
    }                                                                     \
    __builtin_amdgcn_s_setprio(0);                                        \
    WVM(VMP0);                                                            \
    BAR();                                                                \
    SBAR0(); /* keep ph1's ds_reads below the cross-wave barrier */       \
    /* ---- phase 1: mh1 ---- */                                          \
    if (ST) {                                                             \
      STG_A(0, (ANEXT) + 0, KB1);                                         \
      STG_A(128, (ANEXT) + 16384, KB1);                                   \
      STG_A(64, (ANEXT) + 8192, KB1);                                     \
      STG_A(192, (ANEXT) + 24576, KB1);                                   \
    }                                                                     \
    __builtin_amdgcn_s_setprio(1);                                        \
    _Pragma("unroll") for (int q2 = 0; q2 < 4; ++q2) {                    \
      LDA4(1, q2);                                                        \
      MQ16(1, q2);                                                        \
    }                                                                     \
    __builtin_amdgcn_s_setprio(0);                                        \
    WVM(VMP1);                                                            \
    BAR();                                                                \
    SBAR0(); /* keep next tile's ds_reads below the barrier */            \
  } while (0)

__global__ __launch_bounds__(512, 2) void gemm_fp8_kernel(
    const unsigned char* __restrict__ A, const unsigned char* __restrict__ B,
    const float* __restrict__ bias, const unsigned* __restrict__ amax_bits,
    float* __restrict__ out) {
  __shared__ __align__(128) unsigned char sh[131072];

  const int tid = threadIdx.x;
  const int lane = tid & 63;
  const int wave = tid >> 6;
  const int wr = wave >> 2, wc = wave & 3;  // 2 x 4 wave grid
  const int lane15 = lane & 15;

  // XCD-bijective block swizzle (nwg = 2048, 2048 % 8 == 0)
  const int bid = (int)blockIdx.y * 64 + (int)blockIdx.x;
  const int swz = (bid & 7) * 256 + (bid >> 3);
  const size_t m0 = (size_t)(swz >> 6) * 256;  // 32 M-blocks
  const size_t n0 = (size_t)(swz & 63) * 256;  // 64 N-blocks

  const float sx = 448.f / fmaxf(__uint_as_float(amax_bits[0]), 1e-12f);
  const float sk = 448.f / fmaxf(__uint_as_float(amax_bits[1]), 1e-12f);
  const float inv_s = 1.f / (sx * sk);

  // Staging: thread t moves 16B; LDS dest linear (quarter base + t*16),
  // global source chunk pre-swizzled: chunk = (t&7) ^ (row&7).
  const int srow = tid >> 3;                          // 0..63 within quarter
  const int schunk = (((tid & 7) ^ (srow & 7)) << 4); // byte offset 0..112
  const unsigned char* gA = A + (m0 + srow) * D_DIM + schunk;
  const unsigned char* gB = B + (n0 + srow) * D_DIM + schunk;
  const int ldst = tid * 16;

  // Fragment reads: row = <frag base> + lane15; k-byte kb = ks*32 + g*8,
  // g = lane>>4.  Swizzled LDS offset low bits = kb ^ ((row&7)<<4); since
  // row&7 == lane&7, precompute kgs and XOR ks<<5 per read (bits 5-6 only;
  // frag-base offsets are multiples of 2048 so adds don't carry into them).
  const int kgs = (((lane >> 4) << 3) ^ ((lane & 7) << 4));
  const int arow = (wr * 128 + lane15) * 128 + kgs;          // + buf*32768
  const int brow = 65536 + (wc * 64 + lane15) * 128 + kgs;   // + buf*32768

  f32x4 acc[8][4];
#pragma unroll
  for (int i = 0; i < 8; ++i)
#pragma unroll
    for (int j = 0; j < 4; ++j) acc[i][j] = (f32x4){0.f, 0.f, 0.f, 0.f};
  long long aR[4];
  long long bR[4][4];

  // Prologue: stage K-tile 0 into buf 0 (8 quarters), full drain once.
  STG_B(0, 0, 0);
  STG_B(128, 16384, 0);
  STG_B(64, 8192, 0);
  STG_B(192, 24576, 0);
  STG_A(0, 0, 0);
  STG_A(128, 16384, 0);
  STG_A(64, 8192, 0);
  STG_A(192, 24576, 0);
  asm volatile("s_waitcnt vmcnt(0)" ::: "memory");
  BAR();
  SBAR0();

  // Main loop: 32 K-tiles; 2 bodies/iter so buffer offsets are compile-time.
  // Final tile peeled: stages nothing -> ph0 must drain to 0.
  for (int tp = 0; tp < 15; ++tp) {
    const size_t kb1a = (size_t)(2 * tp + 1) * 128;
    const size_t kb1b = (size_t)(2 * tp + 2) * 128;
    TILE2(0, 32768, kb1a, true, 4, 2);
    TILE2(32768, 0, kb1b, true, 4, 2);
  }
  TILE2(0, 32768, (size_t)31 * 128, true, 4, 2);
  TILE2(32768, 0, (size_t)0, false, 0, 0);

  // Epilogue: C/D layout col=lane&15, row=(lane>>4)*4+r.
  const int q4 = (lane >> 4) << 2;
  float bj[4];
#pragma unroll
  for (int j = 0; j < 4; ++j)
    bj[j] = bias[n0 + wc * 64 + j * 16 + lane15];

#pragma unroll
  for (int i = 0; i < 8; ++i) {
    const size_t grow_base = m0 + (size_t)(wr * 128 + i * 16 + q4);
#pragma unroll
    for (int r = 0; r < 4; ++r) {
      float* orow = out + (grow_base + r) * U_DIM + n0 + wc * 64 + lane15;
#pragma unroll
      for (int j = 0; j < 4; ++j) {
        float v = acc[i][j][r] * inv_s + bj[j];
        // tanh-approx gelu, overflow-safe tanh form
        float uu = 0.7978845608028654f * (v + 0.044715f * v * v * v);
        float e = __expf(2.f * uu);
        float th = 1.f - 2.f / (e + 1.f);
        orow[j * 16] = 0.5f * v * (1.f + th);
      }
    }
  }
}

}  // namespace

extern "C" void kernel_launch(void* const* d_in, const int* in_sizes, int n_in,
                              void* d_out, int out_size, void* d_ws,
                              size_t ws_size, hipStream_t stream) {
  const float* x = (const float*)d_in[0];
  const float* kern = (const float*)d_in[1];
  const float* bias = (const float*)d_in[2];
  float* out = (float*)d_out;

  unsigned char* ws = (unsigned char*)d_ws;
  unsigned* amax_bits = (unsigned*)ws;  // [0]=amax(x) bits, [1]=amax(kernel)
  unsigned char* xq = ws + 256;                                  // 32 MB
  unsigned char* kqt = ws + 256 + (size_t)T_DIM * D_DIM;         // 64 MB

  // ws is poisoned 0xAA before every call — zero the amax accumulators.
  hipMemsetAsync(d_ws, 0, 8, stream);

  amax_kernel<<<2048, 256, 0, stream>>>((const float4*)x, T_DIM * D_DIM / 4,
                                        amax_bits + 0);
  amax_kernel<<<4096, 256, 0, stream>>>((const float4*)kern, D_DIM * U_DIM / 4,
                                        amax_bits + 1);
  quant_x_kernel<<<2048, 256, 0, stream>>>((const float4*)x, (unsigned*)xq,
                                           T_DIM * D_DIM / 4, amax_bits);
  quant_kT_kernel<<<dim3(U_DIM / 64, D_DIM / 64), 256, 0, stream>>>(
      kern, kqt, amax_bits);
  gemm_fp8_kernel<<<dim3(U_DIM / 256, T_DIM / 256), 512, 0, stream>>>(
      xq, kqt, bias, amax_bits, out);
}